// Round 5
// baseline (136.726 us; speedup 1.0000x reference)
//
#include <hip/hip_runtime.h>

typedef __bf16 bf16x8 __attribute__((ext_vector_type(8)));
typedef __bf16 bf16x4 __attribute__((ext_vector_type(4)));
typedef __bf16 bf16x2 __attribute__((ext_vector_type(2)));
typedef float f32x4 __attribute__((ext_vector_type(4)));
typedef float f32x16 __attribute__((ext_vector_type(16)));
typedef short s16x4 __attribute__((ext_vector_type(4)));
typedef unsigned int u32x4 __attribute__((ext_vector_type(4)));

#define NB 4
#define NC 64
#define NN 4096
#define SPLIT 8   // key-dim splits for flash

// sc folded into Q at qkv time: softmax uses exp2(q.k * 0.125 * log2(e))
#define QSCALE (0.125f * 1.44269504088896340736f)

#if __has_builtin(__builtin_amdgcn_exp2f)
#define EXP2(x) __builtin_amdgcn_exp2f(x)   // raw v_exp_f32; inputs are O(1)
#else
#define EXP2(x) exp2f(x)
#endif

// direct global->LDS, 16B/lane; dst must be WAVE-UNIFORM base (HW adds lane*16),
// src is per-lane (this is where the swizzle lives).
#define GLL16(src, dst)                                                  \
  __builtin_amdgcn_global_load_lds(                                      \
      (const __attribute__((address_space(1))) void*)(src),              \
      (__attribute__((address_space(3))) void*)(dst), 16, 0, 0)

// ---------------------------------------------------------------------------
// Kernel 1: QKV projection via MFMA, LDS-free, barrier-free.  (unchanged)
// ---------------------------------------------------------------------------
__global__ __launch_bounds__(256) void qkv_kernel(
    const float* __restrict__ x, const float* __restrict__ wqkv,
    const float* __restrict__ bqkv,
    __bf16* __restrict__ Qg, __bf16* __restrict__ Kg, __bf16* __restrict__ Vg)
{
  const int tid = threadIdx.x;
  const int wave = tid >> 6;
  const int lane = tid & 63;
  const int quad = lane >> 4;
  const int l16 = lane & 15;
  const int b = blockIdx.y;
  const int tsel = blockIdx.z;                 // 0=q, 1=k, 2=v
  const int n0 = blockIdx.x * 128 + wave * 32; // wave's 32 n
  const float wscale = (tsel == 0) ? QSCALE : 1.0f;

  // preload W^T B-frags: [ot][ch]; oc = ot*16+l16, c = ch*32+quad*8+j
  bf16x8 wf[4][2];
#pragma unroll
  for (int ot = 0; ot < 4; ot++) {
#pragma unroll
    for (int ch = 0; ch < 2; ch++) {
      const float* wp =
          wqkv + (size_t)(tsel * 64 + ot * 16 + l16) * 64 + ch * 32 + quad * 8;
      const float4 w0 = *(const float4*)wp;
      const float4 w1 = *(const float4*)(wp + 4);
      bf16x8 f;
      f[0] = (__bf16)(w0.x * wscale); f[1] = (__bf16)(w0.y * wscale);
      f[2] = (__bf16)(w0.z * wscale); f[3] = (__bf16)(w0.w * wscale);
      f[4] = (__bf16)(w1.x * wscale); f[5] = (__bf16)(w1.y * wscale);
      f[6] = (__bf16)(w1.z * wscale); f[7] = (__bf16)(w1.w * wscale);
      wf[ot][ch] = f;
    }
  }
  float bv[4];
#pragma unroll
  for (int ot = 0; ot < 4; ot++)
    bv[ot] = bqkv[tsel * 64 + ot * 16 + l16] * wscale;

#pragma unroll
  for (int nt = 0; nt < 2; nt++) {
    const int nb = n0 + nt * 16 + l16;

    // A-frags: x^T[n][c] for c-halves; direct global, 4 lines/instr
    bf16x8 xf[2];
#pragma unroll
    for (int ch = 0; ch < 2; ch++) {
      float v[8];
#pragma unroll
      for (int j = 0; j < 8; j++)
        v[j] = x[(size_t)(b * 64 + ch * 32 + quad * 8 + j) * NN + nb];
      bf16x8 f;
#pragma unroll
      for (int j = 0; j < 8; j++) f[j] = (__bf16)v[j];
      xf[ch] = f;
    }

#pragma unroll
    for (int ot = 0; ot < 4; ot++) {
      f32x4 acc = (f32x4){bv[ot], bv[ot], bv[ot], bv[ot]};
      acc = __builtin_amdgcn_mfma_f32_16x16x32_bf16(xf[0], wf[ot][0], acc, 0, 0, 0);
      acc = __builtin_amdgcn_mfma_f32_16x16x32_bf16(xf[1], wf[ot][1], acc, 0, 0, 0);

      if (tsel < 2) {
        __bf16* dst = (tsel == 0) ? Qg : Kg;
#pragma unroll
        for (int r = 0; r < 4; r++)
          dst[(size_t)(b * NN + n0 + nt * 16 + quad * 4 + r) * 64 + ot * 16 + l16] =
              (__bf16)acc[r];
      } else {
        bf16x4 pv;
#pragma unroll
        for (int r = 0; r < 4; r++) pv[r] = (__bf16)acc[r];
        *(bf16x4*)(Vg + (size_t)(b * 64 + ot * 16 + l16) * NN +
                   n0 + nt * 16 + quad * 4) = pv;
      }
    }
  }
}

// ---------------------------------------------------------------------------
// Kernel 2: flash attention, v6 = 32x32 MFMA structure (m214-style).
// R2/R4 falsified occupancy; R1 falsified latency; R3 VALUBusy/MfmaUtil show
// per-instruction overhead (5:1 VALU:MFMA) is the bottleneck.  32x32x16
// MFMAs cut MFMA instr count 2.7x, LDS reads 3x, pack/addr VALU ~4x per FLOP.
//   QK^T: S[key=64][q=32] per wave = 2 keygroups x 4 c-slice chained MFMAs.
//     A = K-frag [key=lane&31][c=8h+j], B = Q-frag [c][q=lane&31] (regs).
//     C layout: col=q=lane&31, row=key=(reg&3)+8*(reg>>2)+4h  [m74/m101].
//   Softmax: per-lane 16 p per keygroup; bf16 pair-pack + v_permlane32_swap
//     redistributes across lane-halves into PV B-operand regs (T12; the
//     pairing swap(pk(p0,p1), pk(p4,p5)) reproduces the guide's recipe).
//   PV: O^T[c=64][q=32] += V^T x P^T, 2 cgroups x 4 key-slices.
//   Epilogue: same redistribution on O, proj via 32x32 MFMAs.
// Staging/swizzle identical to R1 (GLL16, chunk^(row&7) involution); loop
// unrolled x2 so LDS bases are compile-time.  1 barrier/tile.  No setprio.
// grid(32, B, SPLIT) = 1024 blocks = 4/CU; LDS 32KB/block; VGPR <= 128.
// ---------------------------------------------------------------------------
__global__ __launch_bounds__(256, 4) void flash_kernel(
    const __bf16* __restrict__ Q, const __bf16* __restrict__ K,
    const __bf16* __restrict__ V, const float* __restrict__ wproj,
    __bf16* __restrict__ Opart, float* __restrict__ lpart)
{
  const int b = blockIdx.y;
  const int s = blockIdx.z;
  const int tid = threadIdx.x;
  const int wave = tid >> 6;
  const int lane = tid & 63;
  const int l32 = lane & 31;
  const int h = lane >> 5;

  __shared__ __bf16 KB[2][64 * 64];   // [buf][key][c], chunk-swizzled
  __shared__ __bf16 VB[2][64 * 64];   // [buf][c][key], chunk-swizzled

  const int q0 = blockIdx.x * 128 + wave * 32;   // wave's 32 q

  // Q B-frags: qf[cs][j] = Q[q0+l32][cs*16 + h*8 + j]
  bf16x8 qf[4];
  {
    const __bf16* qrow = Q + ((size_t)(b * NN + q0 + l32)) * 64 + h * 8;
    qf[0] = *(const bf16x8*)(qrow);
    qf[1] = *(const bf16x8*)(qrow + 16);
    qf[2] = *(const bf16x8*)(qrow + 32);
    qf[3] = *(const bf16x8*)(qrow + 48);
  }

  // swizzled read offsets: logical chunk (2i+h) of row (row&7==lane&7)
  int koff[4];
#pragma unroll
  for (int i = 0; i < 4; i++) koff[i] = ((2 * i + h) ^ (lane & 7)) << 3;

  // ---- staging geometry (identical to R1): 512 16B-chunks per tensor tile;
  // wave w owns chunks [w*128, w*128+128) as 2 instrs.  LDS linear in chunk;
  // global source pre-swizzled: chunk c -> row r=c>>3, col chunk (c&7)^(r&7).
  const int c0 = wave * 128 + lane;
  const int c1 = c0 + 64;
  const int r0 = c0 >> 3, r1 = c1 >> 3;
  const int k0 = (c0 & 7) ^ (r0 & 7);
  const int k1 = (c1 & 7) ^ (r1 & 7);
  const int kbeg = s * (NN / SPLIT);
  const __bf16* Ks0 = K + ((size_t)b * NN + kbeg + r0) * 64 + k0 * 8;
  const __bf16* Ks1 = K + ((size_t)b * NN + kbeg + r1) * 64 + k1 * 8;
  const __bf16* Vs0 = V + ((size_t)(b * 64 + r0)) * NN + kbeg + k0 * 8;
  const __bf16* Vs1 = V + ((size_t)(b * 64 + r1)) * NN + kbeg + k1 * 8;
  const int db0 = wave * 1024;
  const int db1 = db0 + 512;

#define STAGE(BUF, T)                                                    \
  {                                                                      \
    GLL16(Ks0 + (size_t)(T) * 4096, &KB[BUF][db0]);                      \
    GLL16(Ks1 + (size_t)(T) * 4096, &KB[BUF][db1]);                      \
    GLL16(Vs0 + (T) * 64, &VB[BUF][db0]);                                \
    GLL16(Vs1 + (T) * 64, &VB[BUF][db1]);                                \
  }

  f32x16 oacc[2] = {};    // O^T: row c = cg*32+(reg&3)+8*(reg>>2)+4h, col q=l32
  float l = 0.f;

  STAGE(0, 0);
  __syncthreads();        // drains vmcnt(0): tile 0 resident

#define TILE_COMPUTE(BUF)                                                \
  {                                                                      \
    u32x4 bw[4];                                                         \
    _Pragma("unroll")                                                    \
    for (int kg = 0; kg < 2; kg++) {                                     \
      f32x16 sa = {};                                                    \
      _Pragma("unroll")                                                  \
      for (int cs = 0; cs < 4; cs++) {                                   \
        const bf16x8 kf =                                                \
            *(const bf16x8*)(&KB[BUF][(kg * 32 + l32) * 64 + koff[cs]]); \
        sa = __builtin_amdgcn_mfma_f32_32x32x16_bf16(kf, qf[cs], sa, 0, 0, 0); \
      }                                                                  \
      _Pragma("unroll")                                                  \
      for (int i = 0; i < 16; i++) sa[i] = EXP2(sa[i]);                  \
      l += ((sa[0] + sa[1]) + (sa[2] + sa[3])) +                         \
           ((sa[4] + sa[5]) + (sa[6] + sa[7])) +                         \
           ((sa[8] + sa[9]) + (sa[10] + sa[11])) +                       \
           ((sa[12] + sa[13]) + (sa[14] + sa[15]));                      \
      unsigned w[8];                                                     \
      _Pragma("unroll")                                                  \
      for (int i = 0; i < 8; i++) {                                      \
        bf16x2 t2;                                                       \
        t2[0] = (__bf16)sa[2 * i]; t2[1] = (__bf16)sa[2 * i + 1];        \
        w[i] = __builtin_bit_cast(unsigned, t2);                         \
      }                                                                  \
      asm("v_permlane32_swap_b32 %0, %1" : "+v"(w[0]), "+v"(w[2]));      \
      asm("v_permlane32_swap_b32 %0, %1" : "+v"(w[1]), "+v"(w[3]));      \
      asm("v_permlane32_swap_b32 %0, %1" : "+v"(w[4]), "+v"(w[6]));      \
      asm("v_permlane32_swap_b32 %0, %1" : "+v"(w[5]), "+v"(w[7]));      \
      bw[kg * 2]     = (u32x4){w[0], w[1], w[2], w[3]};                  \
      bw[kg * 2 + 1] = (u32x4){w[4], w[5], w[6], w[7]};                  \
    }                                                                    \
    _Pragma("unroll")                                                    \
    for (int cg = 0; cg < 2; cg++) {                                     \
      _Pragma("unroll")                                                  \
      for (int ks = 0; ks < 4; ks++) {                                   \
        const bf16x8 va =                                                \
            *(const bf16x8*)(&VB[BUF][(cg * 32 + l32) * 64 + koff[ks]]); \
        oacc[cg] = __builtin_amdgcn_mfma_f32_32x32x16_bf16(              \
            va, __builtin_bit_cast(bf16x8, bw[ks]), oacc[cg], 0, 0, 0);  \
      }                                                                  \
    }                                                                    \
  }

  const int NT = (NN / SPLIT) / 64;   // 8 tiles of 64 keys (even)
#pragma unroll 1
  for (int t = 0; t < NT; t += 2) {
    if (t + 1 < NT) STAGE(1, t + 1);
    TILE_COMPUTE(0);
    __syncthreads();                   // buf1 resident; buf0 free
    if (t + 2 < NT) STAGE(0, t + 2);
    TILE_COMPUTE(1);
    if (t + 2 < NT) __syncthreads();   // buf0 resident; buf1 free
  }

  // ---- epilogue 1: l reduction (lane-halves hold complementary keys) ----
  l += __shfl_xor(l, 32);
  if (h == 0)
    lpart[((size_t)(s * NB + b)) * NN + q0 + l32] = l;

  // ---- epilogue 2: fused proj.  Po^T = Wp * O^T (32x32 MFMAs) -----------
  u32x4 ow[4];
#pragma unroll
  for (int cg = 0; cg < 2; cg++) {
    unsigned w[8];
#pragma unroll
    for (int i = 0; i < 8; i++) {
      bf16x2 t2;
      t2[0] = (__bf16)oacc[cg][2 * i]; t2[1] = (__bf16)oacc[cg][2 * i + 1];
      w[i] = __builtin_bit_cast(unsigned, t2);
    }
    asm("v_permlane32_swap_b32 %0, %1" : "+v"(w[0]), "+v"(w[2]));
    asm("v_permlane32_swap_b32 %0, %1" : "+v"(w[1]), "+v"(w[3]));
    asm("v_permlane32_swap_b32 %0, %1" : "+v"(w[4]), "+v"(w[6]));
    asm("v_permlane32_swap_b32 %0, %1" : "+v"(w[5]), "+v"(w[7]));
    ow[cg * 2]     = (u32x4){w[0], w[1], w[2], w[3]};
    ow[cg * 2 + 1] = (u32x4){w[4], w[5], w[6], w[7]};
  }

#pragma unroll
  for (int cog = 0; cog < 2; cog++) {
    f32x16 po = {};
#pragma unroll
    for (int cs = 0; cs < 4; cs++) {
      const float* wp = wproj + (size_t)(cog * 32 + l32) * 64 + cs * 16 + h * 8;
      const float4 w0 = *(const float4*)wp;
      const float4 w1 = *(const float4*)(wp + 4);
      bf16x8 wa;
      wa[0] = (__bf16)w0.x; wa[1] = (__bf16)w0.y;
      wa[2] = (__bf16)w0.z; wa[3] = (__bf16)w0.w;
      wa[4] = (__bf16)w1.x; wa[5] = (__bf16)w1.y;
      wa[6] = (__bf16)w1.z; wa[7] = (__bf16)w1.w;
      po = __builtin_amdgcn_mfma_f32_32x32x16_bf16(
          wa, __builtin_bit_cast(bf16x8, ow[cs]), po, 0, 0, 0);
    }
#pragma unroll
    for (int reg = 0; reg < 16; reg++) {
      const int co = cog * 32 + (reg & 3) + 8 * (reg >> 2) + 4 * h;
      Opart[(((size_t)(s * NB + b)) * 64 + co) * NN + q0 + l32] =
          (__bf16)po[reg];
    }
  }
#undef STAGE
#undef TILE_COMPUTE
}

// ---------------------------------------------------------------------------
// Kernel 3: slim combine — sum proj-space split partials, 1/l, + bias +
// residual.  (unchanged)
// ---------------------------------------------------------------------------
__global__ __launch_bounds__(256) void combine_kernel(
    const __bf16* __restrict__ Opart, const float* __restrict__ lpart,
    const float* __restrict__ bproj, const float* __restrict__ x,
    float* __restrict__ out)
{
  const int b = blockIdx.y;
  const int n0 = blockIdx.x * 32;
  const int tid = threadIdx.x;

  __shared__ float linv[32];
  if (tid < 32) {
    float lt = 0.f;
#pragma unroll
    for (int s = 0; s < SPLIT; s++)
      lt += lpart[((size_t)(s * NB + b)) * NN + n0 + tid];
    linv[tid] = 1.0f / lt;
  }
  __syncthreads();

  const int c = tid >> 2;
  const int n8 = (tid & 3) * 8;

  float o[8];
#pragma unroll
  for (int j = 0; j < 8; j++) o[j] = 0.f;
#pragma unroll
  for (int s = 0; s < SPLIT; s++) {
    const bf16x8 v = *(const bf16x8*)(
        Opart + (((size_t)(s * NB + b)) * 64 + c) * NN + n0 + n8);
#pragma unroll
    for (int j = 0; j < 8; j++) o[j] += (float)v[j];
  }

  const float bb = bproj[c];
  const float4 li0 = *(const float4*)&linv[n8];
  const float4 li1 = *(const float4*)&linv[n8 + 4];
  const size_t base = ((size_t)(b * 64 + c)) * NN + n0 + n8;
  const float4 x0 = *(const float4*)&x[base];
  const float4 x1 = *(const float4*)&x[base + 4];
  float4 r0, r1;
  r0.x = o[0] * li0.x + bb + x0.x;  r0.y = o[1] * li0.y + bb + x0.y;
  r0.z = o[2] * li0.z + bb + x0.z;  r0.w = o[3] * li0.w + bb + x0.w;
  r1.x = o[4] * li1.x + bb + x1.x;  r1.y = o[5] * li1.y + bb + x1.y;
  r1.z = o[6] * li1.z + bb + x1.z;  r1.w = o[7] * li1.w + bb + x1.w;
  *(float4*)&out[base] = r0;
  *(float4*)&out[base + 4] = r1;
}

extern "C" void kernel_launch(void* const* d_in, const int* in_sizes, int n_in,
                              void* d_out, int out_size, void* d_ws, size_t ws_size,
                              hipStream_t stream) {
  const float* x     = (const float*)d_in[0];
  const float* wqkv  = (const float*)d_in[1];
  const float* bqkv  = (const float*)d_in[2];
  const float* wproj = (const float*)d_in[3];
  const float* bproj = (const float*)d_in[4];
  float* out = (float*)d_out;

  // Workspace: Q[0,2M) K[2,4M) V[4,6M) Opart[6,22M) lpart[23,23.5M)
  char* ws = (char*)d_ws;
  __bf16* Q     = (__bf16*)(ws);
  __bf16* K     = (__bf16*)(ws + (2u << 20));
  __bf16* V     = (__bf16*)(ws + (4u << 20));
  __bf16* Opart = (__bf16*)(ws + (6u << 20));   // [S,B,C,N] = 16 MiB
  float*  lpart = (float*)(ws + (23u << 20));   // SPLIT*B*N*4 = 512 KiB

  qkv_kernel<<<dim3(32, NB, 3), 256, 0, stream>>>(x, wqkv, bqkv, Q, K, V);
  flash_kernel<<<dim3(32, NB, SPLIT), 256, 0, stream>>>(Q, K, V, wproj,
                                                        Opart, lpart);
  combine_kernel<<<dim3(128, NB), 256, 0, stream>>>(Opart, lpart, bproj, x,
                                                    out);
}

// Round 7
// 107.437 us; speedup vs baseline: 1.2726x; 1.2726x over previous
//
#include <hip/hip_runtime.h>

typedef __bf16 bf16x8 __attribute__((ext_vector_type(8)));
typedef __bf16 bf16x4 __attribute__((ext_vector_type(4)));
typedef __bf16 bf16x2 __attribute__((ext_vector_type(2)));
typedef float f32x4 __attribute__((ext_vector_type(4)));
typedef float f32x16 __attribute__((ext_vector_type(16)));
typedef short s16x4 __attribute__((ext_vector_type(4)));
typedef unsigned int u32x4 __attribute__((ext_vector_type(4)));

#define NB 4
#define NC 64
#define NN 4096
#define SPLIT 8   // key-dim splits for flash

// sc folded into Q at qkv time: softmax uses exp2(q.k * 0.125 * log2(e))
#define QSCALE (0.125f * 1.44269504088896340736f)

#if __has_builtin(__builtin_amdgcn_exp2f)
#define EXP2(x) __builtin_amdgcn_exp2f(x)   // raw v_exp_f32; inputs are O(1)
#else
#define EXP2(x) exp2f(x)
#endif

// direct global->LDS, 16B/lane; dst must be WAVE-UNIFORM base (HW adds lane*16),
// src is per-lane (this is where the swizzle lives).
#define GLL16(src, dst)                                                  \
  __builtin_amdgcn_global_load_lds(                                      \
      (const __attribute__((address_space(1))) void*)(src),              \
      (__attribute__((address_space(3))) void*)(dst), 16, 0, 0)

// v_permlane32_swap_b32 is an INVOLUTION with two tied read-write operands.
// It MUST be volatile: a non-volatile asm may be rematerialized/duplicated,
// and a duplicated involution = identity (R6 failure: absmax 0.21 from
// silently un-swapped P-halves under tight regalloc).  sched_barrier(0)
// pins the cluster so register-only ops can't be moved across it.
#define PLSWAP(a, b)                                                     \
  asm volatile("v_permlane32_swap_b32 %0, %1" : "+v"(a), "+v"(b))

// ---------------------------------------------------------------------------
// Kernel 1: QKV projection via MFMA, LDS-free, barrier-free.  (unchanged)
// ---------------------------------------------------------------------------
__global__ __launch_bounds__(256) void qkv_kernel(
    const float* __restrict__ x, const float* __restrict__ wqkv,
    const float* __restrict__ bqkv,
    __bf16* __restrict__ Qg, __bf16* __restrict__ Kg, __bf16* __restrict__ Vg)
{
  const int tid = threadIdx.x;
  const int wave = tid >> 6;
  const int lane = tid & 63;
  const int quad = lane >> 4;
  const int l16 = lane & 15;
  const int b = blockIdx.y;
  const int tsel = blockIdx.z;                 // 0=q, 1=k, 2=v
  const int n0 = blockIdx.x * 128 + wave * 32; // wave's 32 n
  const float wscale = (tsel == 0) ? QSCALE : 1.0f;

  // preload W^T B-frags: [ot][ch]; oc = ot*16+l16, c = ch*32+quad*8+j
  bf16x8 wf[4][2];
#pragma unroll
  for (int ot = 0; ot < 4; ot++) {
#pragma unroll
    for (int ch = 0; ch < 2; ch++) {
      const float* wp =
          wqkv + (size_t)(tsel * 64 + ot * 16 + l16) * 64 + ch * 32 + quad * 8;
      const float4 w0 = *(const float4*)wp;
      const float4 w1 = *(const float4*)(wp + 4);
      bf16x8 f;
      f[0] = (__bf16)(w0.x * wscale); f[1] = (__bf16)(w0.y * wscale);
      f[2] = (__bf16)(w0.z * wscale); f[3] = (__bf16)(w0.w * wscale);
      f[4] = (__bf16)(w1.x * wscale); f[5] = (__bf16)(w1.y * wscale);
      f[6] = (__bf16)(w1.z * wscale); f[7] = (__bf16)(w1.w * wscale);
      wf[ot][ch] = f;
    }
  }
  float bv[4];
#pragma unroll
  for (int ot = 0; ot < 4; ot++)
    bv[ot] = bqkv[tsel * 64 + ot * 16 + l16] * wscale;

#pragma unroll
  for (int nt = 0; nt < 2; nt++) {
    const int nb = n0 + nt * 16 + l16;

    // A-frags: x^T[n][c] for c-halves; direct global, 4 lines/instr
    bf16x8 xf[2];
#pragma unroll
    for (int ch = 0; ch < 2; ch++) {
      float v[8];
#pragma unroll
      for (int j = 0; j < 8; j++)
        v[j] = x[(size_t)(b * 64 + ch * 32 + quad * 8 + j) * NN + nb];
      bf16x8 f;
#pragma unroll
      for (int j = 0; j < 8; j++) f[j] = (__bf16)v[j];
      xf[ch] = f;
    }

#pragma unroll
    for (int ot = 0; ot < 4; ot++) {
      f32x4 acc = (f32x4){bv[ot], bv[ot], bv[ot], bv[ot]};
      acc = __builtin_amdgcn_mfma_f32_16x16x32_bf16(xf[0], wf[ot][0], acc, 0, 0, 0);
      acc = __builtin_amdgcn_mfma_f32_16x16x32_bf16(xf[1], wf[ot][1], acc, 0, 0, 0);

      if (tsel < 2) {
        __bf16* dst = (tsel == 0) ? Qg : Kg;
#pragma unroll
        for (int r = 0; r < 4; r++)
          dst[(size_t)(b * NN + n0 + nt * 16 + quad * 4 + r) * 64 + ot * 16 + l16] =
              (__bf16)acc[r];
      } else {
        bf16x4 pv;
#pragma unroll
        for (int r = 0; r < 4; r++) pv[r] = (__bf16)acc[r];
        *(bf16x4*)(Vg + (size_t)(b * 64 + ot * 16 + l16) * NN +
                   n0 + nt * 16 + quad * 4) = pv;
      }
    }
  }
}

// ---------------------------------------------------------------------------
// Kernel 2: flash attention, v8 = v7 (32x32 MFMA, spill-free) with VOLATILE
// permlane swaps.  R6 failed with math bit-identical to passing R5 -> the
// difference entered via codegen; non-volatile involution asm with tied
// "+v,+v" operands can be duplicated (dup = identity = un-swapped P).  Fix:
// asm volatile + sched_barrier(0) after each swap cluster.  All layouts
// (verified by R5 pass):
//   QK^T: S[key][q=32], A=K-frag, B=Q-frag; C col=q=l32,
//     row=key=(reg&3)+8*(reg>>2)+4h  [m74/m101].
//   Softmax: per-lane 16 p/keygroup; bf16 pair-pack + permlane32_swap.
//   PV per keygroup (minimal live state): S(kg) -> exp/pack -> 4 PV MFMAs.
//   Epilogue: same redistribution on O, proj via 32x32 MFMAs.
// grid(32, B, SPLIT) = 1024 blocks; LDS 32KB; 1 barrier/tile; no setprio;
// __launch_bounds__(256,2) so the allocator sizes freely (no forced spill).
// ---------------------------------------------------------------------------
__global__ __launch_bounds__(256, 2) void flash_kernel(
    const __bf16* __restrict__ Q, const __bf16* __restrict__ K,
    const __bf16* __restrict__ V, const float* __restrict__ wproj,
    __bf16* __restrict__ Opart, float* __restrict__ lpart)
{
  const int b = blockIdx.y;
  const int s = blockIdx.z;
  const int tid = threadIdx.x;
  const int wave = tid >> 6;
  const int lane = tid & 63;
  const int l32 = lane & 31;
  const int h = lane >> 5;

  __shared__ __bf16 KB[2][64 * 64];   // [buf][key][c], chunk-swizzled
  __shared__ __bf16 VB[2][64 * 64];   // [buf][c][key], chunk-swizzled

  const int q0 = blockIdx.x * 128 + wave * 32;   // wave's 32 q

  // Q B-frags: qf[cs][j] = Q[q0+l32][cs*16 + h*8 + j]
  bf16x8 qf[4];
  {
    const __bf16* qrow = Q + ((size_t)(b * NN + q0 + l32)) * 64 + h * 8;
    qf[0] = *(const bf16x8*)(qrow);
    qf[1] = *(const bf16x8*)(qrow + 16);
    qf[2] = *(const bf16x8*)(qrow + 32);
    qf[3] = *(const bf16x8*)(qrow + 48);
  }

  // swizzled read offsets: logical chunk (2i+h) of row (row&7==lane&7)
  int koff[4];
#pragma unroll
  for (int i = 0; i < 4; i++) koff[i] = ((2 * i + h) ^ (lane & 7)) << 3;

  // ---- staging geometry (identical to R1): 512 16B-chunks per tensor tile;
  // wave w owns chunks [w*128, w*128+128) as 2 instrs.  LDS linear in chunk;
  // global source pre-swizzled: chunk c -> row r=c>>3, col chunk (c&7)^(r&7).
  const int c0 = wave * 128 + lane;
  const int c1 = c0 + 64;
  const int r0 = c0 >> 3, r1 = c1 >> 3;
  const int k0 = (c0 & 7) ^ (r0 & 7);
  const int k1 = (c1 & 7) ^ (r1 & 7);
  const int kbeg = s * (NN / SPLIT);
  const __bf16* Ks0 = K + ((size_t)b * NN + kbeg + r0) * 64 + k0 * 8;
  const __bf16* Ks1 = K + ((size_t)b * NN + kbeg + r1) * 64 + k1 * 8;
  const __bf16* Vs0 = V + ((size_t)(b * 64 + r0)) * NN + kbeg + k0 * 8;
  const __bf16* Vs1 = V + ((size_t)(b * 64 + r1)) * NN + kbeg + k1 * 8;
  const int db0 = wave * 1024;
  const int db1 = db0 + 512;

#define STAGE(BUF, T)                                                    \
  {                                                                      \
    GLL16(Ks0 + (size_t)(T) * 4096, &KB[BUF][db0]);                      \
    GLL16(Ks1 + (size_t)(T) * 4096, &KB[BUF][db1]);                      \
    GLL16(Vs0 + (T) * 64, &VB[BUF][db0]);                                \
    GLL16(Vs1 + (T) * 64, &VB[BUF][db1]);                                \
  }

  f32x16 oacc[2] = {};    // O^T: row c = cg*32+(reg&3)+8*(reg>>2)+4h, col q=l32
  float l = 0.f;

  STAGE(0, 0);
  __syncthreads();        // drains vmcnt(0): tile 0 resident

  // Per keygroup: S -> exp -> pack -> PV immediately (minimal live state).
#define TILE_COMPUTE(BUF)                                                \
  {                                                                      \
    _Pragma("unroll")                                                    \
    for (int kg = 0; kg < 2; kg++) {                                     \
      f32x16 sa = {};                                                    \
      _Pragma("unroll")                                                  \
      for (int cs = 0; cs < 4; cs++) {                                   \
        const bf16x8 kf =                                                \
            *(const bf16x8*)(&KB[BUF][(kg * 32 + l32) * 64 + koff[cs]]); \
        sa = __builtin_amdgcn_mfma_f32_32x32x16_bf16(kf, qf[cs], sa, 0, 0, 0); \
      }                                                                  \
      _Pragma("unroll")                                                  \
      for (int i = 0; i < 16; i++) sa[i] = EXP2(sa[i]);                  \
      l += ((sa[0] + sa[1]) + (sa[2] + sa[3])) +                         \
           ((sa[4] + sa[5]) + (sa[6] + sa[7])) +                         \
           ((sa[8] + sa[9]) + (sa[10] + sa[11])) +                       \
           ((sa[12] + sa[13]) + (sa[14] + sa[15]));                      \
      unsigned w[8];                                                     \
      _Pragma("unroll")                                                  \
      for (int i = 0; i < 8; i++) {                                      \
        bf16x2 t2;                                                       \
        t2[0] = (__bf16)sa[2 * i]; t2[1] = (__bf16)sa[2 * i + 1];        \
        w[i] = __builtin_bit_cast(unsigned, t2);                         \
      }                                                                  \
      PLSWAP(w[0], w[2]);                                                \
      PLSWAP(w[1], w[3]);                                                \
      PLSWAP(w[4], w[6]);                                                \
      PLSWAP(w[5], w[7]);                                                \
      __builtin_amdgcn_sched_barrier(0);                                 \
      const u32x4 bw0 = (u32x4){w[0], w[1], w[2], w[3]};                 \
      const u32x4 bw1 = (u32x4){w[4], w[5], w[6], w[7]};                 \
      _Pragma("unroll")                                                  \
      for (int cg = 0; cg < 2; cg++) {                                   \
        const bf16x8 va0 = *(const bf16x8*)(                             \
            &VB[BUF][(cg * 32 + l32) * 64 + koff[kg * 2]]);              \
        oacc[cg] = __builtin_amdgcn_mfma_f32_32x32x16_bf16(              \
            va0, __builtin_bit_cast(bf16x8, bw0), oacc[cg], 0, 0, 0);    \
        const bf16x8 va1 = *(const bf16x8*)(                             \
            &VB[BUF][(cg * 32 + l32) * 64 + koff[kg * 2 + 1]]);          \
        oacc[cg] = __builtin_amdgcn_mfma_f32_32x32x16_bf16(              \
            va1, __builtin_bit_cast(bf16x8, bw1), oacc[cg], 0, 0, 0);    \
      }                                                                  \
    }                                                                    \
  }

  const int NT = (NN / SPLIT) / 64;   // 8 tiles of 64 keys (even)
#pragma unroll 1
  for (int t = 0; t < NT; t += 2) {
    if (t + 1 < NT) STAGE(1, t + 1);
    TILE_COMPUTE(0);
    __syncthreads();                   // buf1 resident; buf0 free
    if (t + 2 < NT) STAGE(0, t + 2);
    TILE_COMPUTE(1);
    if (t + 2 < NT) __syncthreads();   // buf0 resident; buf1 free
  }

  // ---- epilogue 1: l reduction (lane-halves hold complementary keys) ----
  l += __shfl_xor(l, 32);
  if (h == 0)
    lpart[((size_t)(s * NB + b)) * NN + q0 + l32] = l;

  // ---- epilogue 2: fused proj.  Po^T = Wp * O^T (32x32 MFMAs) -----------
  u32x4 ow[4];
#pragma unroll
  for (int cg = 0; cg < 2; cg++) {
    unsigned w[8];
#pragma unroll
    for (int i = 0; i < 8; i++) {
      bf16x2 t2;
      t2[0] = (__bf16)oacc[cg][2 * i]; t2[1] = (__bf16)oacc[cg][2 * i + 1];
      w[i] = __builtin_bit_cast(unsigned, t2);
    }
    PLSWAP(w[0], w[2]);
    PLSWAP(w[1], w[3]);
    PLSWAP(w[4], w[6]);
    PLSWAP(w[5], w[7]);
    __builtin_amdgcn_sched_barrier(0);
    ow[cg * 2]     = (u32x4){w[0], w[1], w[2], w[3]};
    ow[cg * 2 + 1] = (u32x4){w[4], w[5], w[6], w[7]};
  }

#pragma unroll
  for (int cog = 0; cog < 2; cog++) {
    f32x16 po = {};
#pragma unroll
    for (int cs = 0; cs < 4; cs++) {
      const float* wp = wproj + (size_t)(cog * 32 + l32) * 64 + cs * 16 + h * 8;
      const float4 w0 = *(const float4*)wp;
      const float4 w1 = *(const float4*)(wp + 4);
      bf16x8 wa;
      wa[0] = (__bf16)w0.x; wa[1] = (__bf16)w0.y;
      wa[2] = (__bf16)w0.z; wa[3] = (__bf16)w0.w;
      wa[4] = (__bf16)w1.x; wa[5] = (__bf16)w1.y;
      wa[6] = (__bf16)w1.z; wa[7] = (__bf16)w1.w;
      po = __builtin_amdgcn_mfma_f32_32x32x16_bf16(
          wa, __builtin_bit_cast(bf16x8, ow[cs]), po, 0, 0, 0);
    }
#pragma unroll
    for (int reg = 0; reg < 16; reg++) {
      const int co = cog * 32 + (reg & 3) + 8 * (reg >> 2) + 4 * h;
      Opart[(((size_t)(s * NB + b)) * 64 + co) * NN + q0 + l32] =
          (__bf16)po[reg];
    }
  }
#undef STAGE
#undef TILE_COMPUTE
}

// ---------------------------------------------------------------------------
// Kernel 3: slim combine — sum proj-space split partials, 1/l, + bias +
// residual.  (unchanged)
// ---------------------------------------------------------------------------
__global__ __launch_bounds__(256) void combine_kernel(
    const __bf16* __restrict__ Opart, const float* __restrict__ lpart,
    const float* __restrict__ bproj, const float* __restrict__ x,
    float* __restrict__ out)
{
  const int b = blockIdx.y;
  const int n0 = blockIdx.x * 32;
  const int tid = threadIdx.x;

  __shared__ float linv[32];
  if (tid < 32) {
    float lt = 0.f;
#pragma unroll
    for (int s = 0; s < SPLIT; s++)
      lt += lpart[((size_t)(s * NB + b)) * NN + n0 + tid];
    linv[tid] = 1.0f / lt;
  }
  __syncthreads();

  const int c = tid >> 2;
  const int n8 = (tid & 3) * 8;

  float o[8];
#pragma unroll
  for (int j = 0; j < 8; j++) o[j] = 0.f;
#pragma unroll
  for (int s = 0; s < SPLIT; s++) {
    const bf16x8 v = *(const bf16x8*)(
        Opart + (((size_t)(s * NB + b)) * 64 + c) * NN + n0 + n8);
#pragma unroll
    for (int j = 0; j < 8; j++) o[j] += (float)v[j];
  }

  const float bb = bproj[c];
  const float4 li0 = *(const float4*)&linv[n8];
  const float4 li1 = *(const float4*)&linv[n8 + 4];
  const size_t base = ((size_t)(b * 64 + c)) * NN + n0 + n8;
  const float4 x0 = *(const float4*)&x[base];
  const float4 x1 = *(const float4*)&x[base + 4];
  float4 r0, r1;
  r0.x = o[0] * li0.x + bb + x0.x;  r0.y = o[1] * li0.y + bb + x0.y;
  r0.z = o[2] * li0.z + bb + x0.z;  r0.w = o[3] * li0.w + bb + x0.w;
  r1.x = o[4] * li1.x + bb + x1.x;  r1.y = o[5] * li1.y + bb + x1.y;
  r1.z = o[6] * li1.z + bb + x1.z;  r1.w = o[7] * li1.w + bb + x1.w;
  *(float4*)&out[base] = r0;
  *(float4*)&out[base + 4] = r1;
}

extern "C" void kernel_launch(void* const* d_in, const int* in_sizes, int n_in,
                              void* d_out, int out_size, void* d_ws, size_t ws_size,
                              hipStream_t stream) {
  const float* x     = (const float*)d_in[0];
  const float* wqkv  = (const float*)d_in[1];
  const float* bqkv  = (const float*)d_in[2];
  const float* wproj = (const float*)d_in[3];
  const float* bproj = (const float*)d_in[4];
  float* out = (float*)d_out;

  // Workspace: Q[0,2M) K[2,4M) V[4,6M) Opart[6,22M) lpart[23,23.5M)
  char* ws = (char*)d_ws;
  __bf16* Q     = (__bf16*)(ws);
  __bf16* K     = (__bf16*)(ws + (2u << 20));
  __bf16* V     = (__bf16*)(ws + (4u << 20));
  __bf16* Opart = (__bf16*)(ws + (6u << 20));   // [S,B,C,N] = 16 MiB
  float*  lpart = (float*)(ws + (23u << 20));   // SPLIT*B*N*4 = 512 KiB

  qkv_kernel<<<dim3(32, NB, 3), 256, 0, stream>>>(x, wqkv, bqkv, Q, K, V);
  flash_kernel<<<dim3(32, NB, SPLIT), 256, 0, stream>>>(Q, K, V, wproj,
                                                        Opart, lpart);
  combine_kernel<<<dim3(128, NB), 256, 0, stream>>>(Opart, lpart, bproj, x,
                                                    out);
}

// Round 8
// 106.714 us; speedup vs baseline: 1.2812x; 1.0068x over previous
//
#include <hip/hip_runtime.h>

typedef __bf16 bf16x8 __attribute__((ext_vector_type(8)));
typedef __bf16 bf16x4 __attribute__((ext_vector_type(4)));
typedef __bf16 bf16x2 __attribute__((ext_vector_type(2)));
typedef float f32x4 __attribute__((ext_vector_type(4)));
typedef float f32x16 __attribute__((ext_vector_type(16)));
typedef short s16x4 __attribute__((ext_vector_type(4)));
typedef unsigned int u32x4 __attribute__((ext_vector_type(4)));

#define NB 4
#define NC 64
#define NN 4096
#define SPLIT 8   // key-dim splits for flash

// sc folded into Q at qkv time: softmax uses exp2(q.k * 0.125 * log2(e))
#define QSCALE (0.125f * 1.44269504088896340736f)

#if __has_builtin(__builtin_amdgcn_exp2f)
#define EXP2(x) __builtin_amdgcn_exp2f(x)   // raw v_exp_f32; inputs are O(1)
#else
#define EXP2(x) exp2f(x)
#endif

#if __has_builtin(__builtin_amdgcn_fdot2_f32_bf16)
#define HAVE_FDOT2 1
#else
#define HAVE_FDOT2 0
#endif

// direct global->LDS, 16B/lane; dst must be WAVE-UNIFORM base (HW adds lane*16),
// src is per-lane (this is where the swizzle lives).
#define GLL16(src, dst)                                                  \
  __builtin_amdgcn_global_load_lds(                                      \
      (const __attribute__((address_space(1))) void*)(src),              \
      (__attribute__((address_space(3))) void*)(dst), 16, 0, 0)

// v_permlane32_swap_b32 is an INVOLUTION with two tied read-write operands.
// It MUST be volatile: a non-volatile asm may be rematerialized/duplicated,
// and a duplicated involution = identity (R6 failure).  volatile prevents
// duplication; data deps through "+v" operands keep scheduling safe, so NO
// sched_barrier is needed (R7's barrier cost cross-phase ILP).
#define PLSWAP(a, b)                                                     \
  asm volatile("v_permlane32_swap_b32 %0, %1" : "+v"(a), "+v"(b))

// ---------------------------------------------------------------------------
// Kernel 1: QKV projection via MFMA, LDS-free, barrier-free.
// v2: x read ONCE per n (tsel loop inside the block) -> x fetch 12->4 MiB.
// grid(64, NB) = 256 blocks; wave owns 16 n; per tsel: reload W^T frags
// (L2-resident, 48 KB total) and compute 4 oc-tiles.
// ---------------------------------------------------------------------------
__global__ __launch_bounds__(256) void qkv_kernel(
    const float* __restrict__ x, const float* __restrict__ wqkv,
    const float* __restrict__ bqkv,
    __bf16* __restrict__ Qg, __bf16* __restrict__ Kg, __bf16* __restrict__ Vg)
{
  const int tid = threadIdx.x;
  const int wave = tid >> 6;
  const int lane = tid & 63;
  const int quad = lane >> 4;
  const int l16 = lane & 15;
  const int b = blockIdx.y;
  const int n0 = blockIdx.x * 64 + wave * 16;  // wave's 16 n
  const int nb = n0 + l16;

  // A-frags: x^T[n][c] for c-halves; direct global, loaded ONCE
  bf16x8 xf[2];
#pragma unroll
  for (int ch = 0; ch < 2; ch++) {
    float v[8];
#pragma unroll
    for (int j = 0; j < 8; j++)
      v[j] = x[(size_t)(b * 64 + ch * 32 + quad * 8 + j) * NN + nb];
    bf16x8 f;
#pragma unroll
    for (int j = 0; j < 8; j++) f[j] = (__bf16)v[j];
    xf[ch] = f;
  }

#pragma unroll 1
  for (int tsel = 0; tsel < 3; tsel++) {
    const float wscale = (tsel == 0) ? QSCALE : 1.0f;

    // W^T B-frags: [ot][ch]; oc = tsel*64+ot*16+l16, c = ch*32+quad*8+j
    bf16x8 wf[4][2];
#pragma unroll
    for (int ot = 0; ot < 4; ot++) {
#pragma unroll
      for (int ch = 0; ch < 2; ch++) {
        const float* wp =
            wqkv + (size_t)(tsel * 64 + ot * 16 + l16) * 64 + ch * 32 + quad * 8;
        const float4 w0 = *(const float4*)wp;
        const float4 w1 = *(const float4*)(wp + 4);
        bf16x8 f;
        f[0] = (__bf16)(w0.x * wscale); f[1] = (__bf16)(w0.y * wscale);
        f[2] = (__bf16)(w0.z * wscale); f[3] = (__bf16)(w0.w * wscale);
        f[4] = (__bf16)(w1.x * wscale); f[5] = (__bf16)(w1.y * wscale);
        f[6] = (__bf16)(w1.z * wscale); f[7] = (__bf16)(w1.w * wscale);
        wf[ot][ch] = f;
      }
    }
    float bv[4];
#pragma unroll
    for (int ot = 0; ot < 4; ot++)
      bv[ot] = bqkv[tsel * 64 + ot * 16 + l16] * wscale;

#pragma unroll
    for (int ot = 0; ot < 4; ot++) {
      f32x4 acc = (f32x4){bv[ot], bv[ot], bv[ot], bv[ot]};
      acc = __builtin_amdgcn_mfma_f32_16x16x32_bf16(xf[0], wf[ot][0], acc, 0, 0, 0);
      acc = __builtin_amdgcn_mfma_f32_16x16x32_bf16(xf[1], wf[ot][1], acc, 0, 0, 0);

      if (tsel < 2) {
        __bf16* dst = (tsel == 0) ? Qg : Kg;
#pragma unroll
        for (int r = 0; r < 4; r++)
          dst[(size_t)(b * NN + n0 + quad * 4 + r) * 64 + ot * 16 + l16] =
              (__bf16)acc[r];
      } else {
        bf16x4 pv;
#pragma unroll
        for (int r = 0; r < 4; r++) pv[r] = (__bf16)acc[r];
        *(bf16x4*)(Vg + (size_t)(b * 64 + ot * 16 + l16) * NN +
                   n0 + quad * 4) = pv;
      }
    }
  }
}

// ---------------------------------------------------------------------------
// Kernel 2: flash attention, v9 = v8 with the scheduler UNSHACKLED.
// Changes vs v8 (R7, passed at ~36us):
//  (1) sched_barrier(0) removed -- volatile alone prevents the R6 dup bug;
//      kg1's QK MFMAs can now overlap kg0's exp/pack/PV (cross-pipe ILP).
//  (2) l-sum via v_dot2_f32_bf16 on the packed P pairs (8 dot2 vs 31 f32
//      adds per kg-pair); l now sums the same bf16-rounded P that PV uses.
// Layouts (verified by R5/R7 passes):
//   QK^T: S[key][q=32], A=K-frag, B=Q-frag; C col=q=l32,
//     row=key=(reg&3)+8*(reg>>2)+4h  [m74/m101].
//   Softmax: per-lane 16 p/keygroup; bf16 pair-pack + permlane32_swap.
//   PV per keygroup: S(kg) -> exp/pack -> 4 PV MFMAs (minimal live state).
//   Epilogue: same redistribution on O, proj via 32x32 MFMAs.
// grid(32, B, SPLIT) = 1024 blocks; LDS 32KB; 1 barrier/tile; no setprio;
// __launch_bounds__(256,2).
// ---------------------------------------------------------------------------
__global__ __launch_bounds__(256, 2) void flash_kernel(
    const __bf16* __restrict__ Q, const __bf16* __restrict__ K,
    const __bf16* __restrict__ V, const float* __restrict__ wproj,
    __bf16* __restrict__ Opart, float* __restrict__ lpart)
{
  const int b = blockIdx.y;
  const int s = blockIdx.z;
  const int tid = threadIdx.x;
  const int wave = tid >> 6;
  const int lane = tid & 63;
  const int l32 = lane & 31;
  const int h = lane >> 5;

  __shared__ __bf16 KB[2][64 * 64];   // [buf][key][c], chunk-swizzled
  __shared__ __bf16 VB[2][64 * 64];   // [buf][c][key], chunk-swizzled

  const int q0 = blockIdx.x * 128 + wave * 32;   // wave's 32 q

  // Q B-frags: qf[cs][j] = Q[q0+l32][cs*16 + h*8 + j]
  bf16x8 qf[4];
  {
    const __bf16* qrow = Q + ((size_t)(b * NN + q0 + l32)) * 64 + h * 8;
    qf[0] = *(const bf16x8*)(qrow);
    qf[1] = *(const bf16x8*)(qrow + 16);
    qf[2] = *(const bf16x8*)(qrow + 32);
    qf[3] = *(const bf16x8*)(qrow + 48);
  }

#if HAVE_FDOT2
  const bf16x2 ones2 = {(__bf16)1.0f, (__bf16)1.0f};
#endif

  // swizzled read offsets: logical chunk (2i+h) of row (row&7==lane&7)
  int koff[4];
#pragma unroll
  for (int i = 0; i < 4; i++) koff[i] = ((2 * i + h) ^ (lane & 7)) << 3;

  // ---- staging geometry (identical to R1): 512 16B-chunks per tensor tile;
  // wave w owns chunks [w*128, w*128+128) as 2 instrs.  LDS linear in chunk;
  // global source pre-swizzled: chunk c -> row r=c>>3, col chunk (c&7)^(r&7).
  const int c0 = wave * 128 + lane;
  const int c1 = c0 + 64;
  const int r0 = c0 >> 3, r1 = c1 >> 3;
  const int k0 = (c0 & 7) ^ (r0 & 7);
  const int k1 = (c1 & 7) ^ (r1 & 7);
  const int kbeg = s * (NN / SPLIT);
  const __bf16* Ks0 = K + ((size_t)b * NN + kbeg + r0) * 64 + k0 * 8;
  const __bf16* Ks1 = K + ((size_t)b * NN + kbeg + r1) * 64 + k1 * 8;
  const __bf16* Vs0 = V + ((size_t)(b * 64 + r0)) * NN + kbeg + k0 * 8;
  const __bf16* Vs1 = V + ((size_t)(b * 64 + r1)) * NN + kbeg + k1 * 8;
  const int db0 = wave * 1024;
  const int db1 = db0 + 512;

#define STAGE(BUF, T)                                                    \
  {                                                                      \
    GLL16(Ks0 + (size_t)(T) * 4096, &KB[BUF][db0]);                      \
    GLL16(Ks1 + (size_t)(T) * 4096, &KB[BUF][db1]);                      \
    GLL16(Vs0 + (T) * 64, &VB[BUF][db0]);                                \
    GLL16(Vs1 + (T) * 64, &VB[BUF][db1]);                                \
  }

  f32x16 oacc[2] = {};    // O^T: row c = cg*32+(reg&3)+8*(reg>>2)+4h, col q=l32
  float l = 0.f;

  STAGE(0, 0);
  __syncthreads();        // drains vmcnt(0): tile 0 resident

  // Per keygroup: S -> exp -> pack -> (dot2 l) -> swap -> PV.
#define TILE_COMPUTE(BUF)                                                \
  {                                                                      \
    _Pragma("unroll")                                                    \
    for (int kg = 0; kg < 2; kg++) {                                     \
      f32x16 sa = {};                                                    \
      _Pragma("unroll")                                                  \
      for (int cs = 0; cs < 4; cs++) {                                   \
        const bf16x8 kf =                                                \
            *(const bf16x8*)(&KB[BUF][(kg * 32 + l32) * 64 + koff[cs]]); \
        sa = __builtin_amdgcn_mfma_f32_32x32x16_bf16(kf, qf[cs], sa, 0, 0, 0); \
      }                                                                  \
      _Pragma("unroll")                                                  \
      for (int i = 0; i < 16; i++) sa[i] = EXP2(sa[i]);                  \
      unsigned w[8];                                                     \
      _Pragma("unroll")                                                  \
      for (int i = 0; i < 8; i++) {                                      \
        bf16x2 t2;                                                       \
        t2[0] = (__bf16)sa[2 * i]; t2[1] = (__bf16)sa[2 * i + 1];        \
        w[i] = __builtin_bit_cast(unsigned, t2);                         \
      }                                                                  \
      LSUM_BLOCK(sa, w)                                                  \
      PLSWAP(w[0], w[2]);                                                \
      PLSWAP(w[1], w[3]);                                                \
      PLSWAP(w[4], w[6]);                                                \
      PLSWAP(w[5], w[7]);                                                \
      const u32x4 bw0 = (u32x4){w[0], w[1], w[2], w[3]};                 \
      const u32x4 bw1 = (u32x4){w[4], w[5], w[6], w[7]};                 \
      _Pragma("unroll")                                                  \
      for (int cg = 0; cg < 2; cg++) {                                   \
        const bf16x8 va0 = *(const bf16x8*)(                             \
            &VB[BUF][(cg * 32 + l32) * 64 + koff[kg * 2]]);              \
        oacc[cg] = __builtin_amdgcn_mfma_f32_32x32x16_bf16(              \
            va0, __builtin_bit_cast(bf16x8, bw0), oacc[cg], 0, 0, 0);    \
        const bf16x8 va1 = *(const bf16x8*)(                             \
            &VB[BUF][(cg * 32 + l32) * 64 + koff[kg * 2 + 1]]);          \
        oacc[cg] = __builtin_amdgcn_mfma_f32_32x32x16_bf16(              \
            va1, __builtin_bit_cast(bf16x8, bw1), oacc[cg], 0, 0, 0);    \
      }                                                                  \
    }                                                                    \
  }

#if HAVE_FDOT2
#define LSUM_BLOCK(sa, w)                                                \
      _Pragma("unroll")                                                  \
      for (int i = 0; i < 8; i++)                                        \
        l = __builtin_amdgcn_fdot2_f32_bf16(                             \
            __builtin_bit_cast(bf16x2, w[i]), ones2, l, false);
#else
#define LSUM_BLOCK(sa, w)                                                \
      l += ((sa[0] + sa[1]) + (sa[2] + sa[3])) +                         \
           ((sa[4] + sa[5]) + (sa[6] + sa[7])) +                         \
           ((sa[8] + sa[9]) + (sa[10] + sa[11])) +                       \
           ((sa[12] + sa[13]) + (sa[14] + sa[15]));
#endif

  const int NT = (NN / SPLIT) / 64;   // 8 tiles of 64 keys (even)
#pragma unroll 1
  for (int t = 0; t < NT; t += 2) {
    if (t + 1 < NT) STAGE(1, t + 1);
    TILE_COMPUTE(0);
    __syncthreads();                   // buf1 resident; buf0 free
    if (t + 2 < NT) STAGE(0, t + 2);
    TILE_COMPUTE(1);
    if (t + 2 < NT) __syncthreads();   // buf0 resident; buf1 free
  }

  // ---- epilogue 1: l reduction (lane-halves hold complementary keys) ----
  l += __shfl_xor(l, 32);
  if (h == 0)
    lpart[((size_t)(s * NB + b)) * NN + q0 + l32] = l;

  // ---- epilogue 2: fused proj.  Po^T = Wp * O^T (32x32 MFMAs) -----------
  u32x4 ow[4];
#pragma unroll
  for (int cg = 0; cg < 2; cg++) {
    unsigned w[8];
#pragma unroll
    for (int i = 0; i < 8; i++) {
      bf16x2 t2;
      t2[0] = (__bf16)oacc[cg][2 * i]; t2[1] = (__bf16)oacc[cg][2 * i + 1];
      w[i] = __builtin_bit_cast(unsigned, t2);
    }
    PLSWAP(w[0], w[2]);
    PLSWAP(w[1], w[3]);
    PLSWAP(w[4], w[6]);
    PLSWAP(w[5], w[7]);
    ow[cg * 2]     = (u32x4){w[0], w[1], w[2], w[3]};
    ow[cg * 2 + 1] = (u32x4){w[4], w[5], w[6], w[7]};
  }

#pragma unroll
  for (int cog = 0; cog < 2; cog++) {
    f32x16 po = {};
#pragma unroll
    for (int cs = 0; cs < 4; cs++) {
      const float* wp = wproj + (size_t)(cog * 32 + l32) * 64 + cs * 16 + h * 8;
      const float4 w0 = *(const float4*)wp;
      const float4 w1 = *(const float4*)(wp + 4);
      bf16x8 wa;
      wa[0] = (__bf16)w0.x; wa[1] = (__bf16)w0.y;
      wa[2] = (__bf16)w0.z; wa[3] = (__bf16)w0.w;
      wa[4] = (__bf16)w1.x; wa[5] = (__bf16)w1.y;
      wa[6] = (__bf16)w1.z; wa[7] = (__bf16)w1.w;
      po = __builtin_amdgcn_mfma_f32_32x32x16_bf16(
          wa, __builtin_bit_cast(bf16x8, ow[cs]), po, 0, 0, 0);
    }
#pragma unroll
    for (int reg = 0; reg < 16; reg++) {
      const int co = cog * 32 + (reg & 3) + 8 * (reg >> 2) + 4 * h;
      Opart[(((size_t)(s * NB + b)) * 64 + co) * NN + q0 + l32] =
          (__bf16)po[reg];
    }
  }
#undef STAGE
#undef TILE_COMPUTE
#undef LSUM_BLOCK
}

// ---------------------------------------------------------------------------
// Kernel 3: slim combine — sum proj-space split partials, 1/l, + bias +
// residual.  (unchanged)
// ---------------------------------------------------------------------------
__global__ __launch_bounds__(256) void combine_kernel(
    const __bf16* __restrict__ Opart, const float* __restrict__ lpart,
    const float* __restrict__ bproj, const float* __restrict__ x,
    float* __restrict__ out)
{
  const int b = blockIdx.y;
  const int n0 = blockIdx.x * 32;
  const int tid = threadIdx.x;

  __shared__ float linv[32];
  if (tid < 32) {
    float lt = 0.f;
#pragma unroll
    for (int s = 0; s < SPLIT; s++)
      lt += lpart[((size_t)(s * NB + b)) * NN + n0 + tid];
    linv[tid] = 1.0f / lt;
  }
  __syncthreads();

  const int c = tid >> 2;
  const int n8 = (tid & 3) * 8;

  float o[8];
#pragma unroll
  for (int j = 0; j < 8; j++) o[j] = 0.f;
#pragma unroll
  for (int s = 0; s < SPLIT; s++) {
    const bf16x8 v = *(const bf16x8*)(
        Opart + (((size_t)(s * NB + b)) * 64 + c) * NN + n0 + n8);
#pragma unroll
    for (int j = 0; j < 8; j++) o[j] += (float)v[j];
  }

  const float bb = bproj[c];
  const float4 li0 = *(const float4*)&linv[n8];
  const float4 li1 = *(const float4*)&linv[n8 + 4];
  const size_t base = ((size_t)(b * 64 + c)) * NN + n0 + n8;
  const float4 x0 = *(const float4*)&x[base];
  const float4 x1 = *(const float4*)&x[base + 4];
  float4 r0, r1;
  r0.x = o[0] * li0.x + bb + x0.x;  r0.y = o[1] * li0.y + bb + x0.y;
  r0.z = o[2] * li0.z + bb + x0.z;  r0.w = o[3] * li0.w + bb + x0.w;
  r1.x = o[4] * li1.x + bb + x1.x;  r1.y = o[5] * li1.y + bb + x1.y;
  r1.z = o[6] * li1.z + bb + x1.z;  r1.w = o[7] * li1.w + bb + x1.w;
  *(float4*)&out[base] = r0;
  *(float4*)&out[base + 4] = r1;
}

extern "C" void kernel_launch(void* const* d_in, const int* in_sizes, int n_in,
                              void* d_out, int out_size, void* d_ws, size_t ws_size,
                              hipStream_t stream) {
  const float* x     = (const float*)d_in[0];
  const float* wqkv  = (const float*)d_in[1];
  const float* bqkv  = (const float*)d_in[2];
  const float* wproj = (const float*)d_in[3];
  const float* bproj = (const float*)d_in[4];
  float* out = (float*)d_out;

  // Workspace: Q[0,2M) K[2,4M) V[4,6M) Opart[6,22M) lpart[23,23.5M)
  char* ws = (char*)d_ws;
  __bf16* Q     = (__bf16*)(ws);
  __bf16* K     = (__bf16*)(ws + (2u << 20));
  __bf16* V     = (__bf16*)(ws + (4u << 20));
  __bf16* Opart = (__bf16*)(ws + (6u << 20));   // [S,B,C,N] = 16 MiB
  float*  lpart = (float*)(ws + (23u << 20));   // SPLIT*B*N*4 = 512 KiB

  qkv_kernel<<<dim3(64, NB), 256, 0, stream>>>(x, wqkv, bqkv, Q, K, V);
  flash_kernel<<<dim3(32, NB, SPLIT), 256, 0, stream>>>(Q, K, V, wproj,
                                                        Opart, lpart);
  combine_kernel<<<dim3(128, NB), 256, 0, stream>>>(Opart, lpart, bproj, x,
                                                    out);
}